// Round 15
// baseline (99.729 us; speedup 1.0000x reference)
//
#include <hip/hip_runtime.h>
#include <hip/hip_bf16.h>

#define B_ 16
#define S_ 512
#define D_ 768
#define E_ 16
#define K_ 4

typedef __attribute__((ext_vector_type(8))) short short8;
typedef __attribute__((ext_vector_type(4))) float f32x4;

#define GLOAD16(gp, lp)                                             \
    __builtin_amdgcn_global_lds_impl(gp, lp)
#undef GLOAD16
#define GLOAD16(gp, lp)                                             \
    __builtin_amdgcn_global_load_lds(                               \
        (const __attribute__((address_space(1))) void*)(gp),        \
        (__attribute__((address_space(3))) void*)(lp), 16, 0, 0)

// ---- KA: x->bf16 + column-mean partials; LAST block does gating + loss ----------------
__global__ void kA_cvt_gate(const float* __restrict__ x,
                            const float* __restrict__ noise,
                            const float* __restrict__ w_gate,
                            const float* __restrict__ w_noise,
                            const float* __restrict__ thr_ptr,
                            __hip_bfloat16* __restrict__ xb,
                            float* __restrict__ partial,
                            float* __restrict__ gates_g,
                            float* __restrict__ loss_out,
                            unsigned int* __restrict__ cnt) {
    int t  = threadIdx.x;          // 0..191
    int b  = blockIdx.x;           // 0..15
    int sc = blockIdx.y;           // 0..15 (s chunk of 32)
    size_t rowbase = ((size_t)b * S_ + (size_t)sc * 32) * D_ + t * 4;

    float4 acc = make_float4(0.f, 0.f, 0.f, 0.f);
    #pragma unroll 8
    for (int s = 0; s < 32; ++s) {
        float4 v = *(const float4*)(x + rowbase + (size_t)s * D_);
        acc.x += v.x; acc.y += v.y; acc.z += v.z; acc.w += v.w;
        __hip_bfloat16 h0 = __float2bfloat16(v.x);
        __hip_bfloat16 h1 = __float2bfloat16(v.y);
        __hip_bfloat16 h2 = __float2bfloat16(v.z);
        __hip_bfloat16 h3 = __float2bfloat16(v.w);
        ushort4 pk;
        pk.x = *(unsigned short*)&h0; pk.y = *(unsigned short*)&h1;
        pk.z = *(unsigned short*)&h2; pk.w = *(unsigned short*)&h3;
        *(ushort4*)((unsigned short*)xb + rowbase + (size_t)s * D_) = pk;
    }
    *(float4*)(partial + ((size_t)sc * B_ + b) * D_ + t * 4) = acc;

    // ---- last-block election (deterministic: exactly one winner per launch;
    //      parity mod 256 is immune to the 0xAA workspace poison) ----
    __threadfence();
    __shared__ unsigned int s_old;
    if (t == 0) s_old = atomicAdd(cnt, 1u);
    __syncthreads();
    if ((s_old & 255u) != 255u) return;
    __threadfence();   // acquire: all 256 blocks' partial stores visible

    // ---- winner tail: full gating for all (b,e) + cv^2 loss ----
    __shared__ float xmT[D_ * B_ / 4][4];        // [d][b] transposed means, 48 KB
    #define XMT(d, bb) xmT[((d) * B_ + (bb)) >> 2][((d) * B_ + (bb)) & 3]
    __shared__ float redc[12][E_][B_], redn[12][E_][B_];   // 24 KB
    __shared__ float s_noisy[B_][E_ + 1], s_clean[B_][E_ + 1], s_std[B_][E_ + 1];
    __shared__ float thrin_s[B_], throut_s[B_];
    __shared__ float gsl[B_][E_], s_imp[E_], s_load[E_];

    // 1) reduce 16 partial chunks -> xmT[d][b]
    for (int j = t; j < 3072; j += 192) {        // j = (b, d4)
        int bb = j / 192, d4 = j % 192;
        f32x4 s = {0.f, 0.f, 0.f, 0.f};
        #pragma unroll
        for (int c = 0; c < 16; ++c)
            s += *(const f32x4*)(partial + ((size_t)c * B_ + bb) * D_ + d4 * 4);
        #pragma unroll
        for (int k2 = 0; k2 < 4; ++k2) XMT(d4 * 4 + k2, bb) = s[k2] * (1.0f / S_);
    }
    __syncthreads();

    // 2) dots: thread (e, sl): 64 d's, all 16 b in vector regs
    {
        int e = t & 15, sl = t >> 4;             // sl 0..11
        f32x4 cl0 = {0,0,0,0}, cl1 = {0,0,0,0}, cl2 = {0,0,0,0}, cl3 = {0,0,0,0};
        f32x4 nz0 = {0,0,0,0}, nz1 = {0,0,0,0}, nz2 = {0,0,0,0}, nz3 = {0,0,0,0};
        #pragma unroll 8
        for (int i = 0; i < 64; ++i) {
            int d = sl * 64 + i;
            float wgv = w_gate [d * E_ + e];
            float wnv = w_noise[d * E_ + e];
            f32x4 x0 = *(const f32x4*)&XMT(d, 0);
            f32x4 x1 = *(const f32x4*)&XMT(d, 4);
            f32x4 x2 = *(const f32x4*)&XMT(d, 8);
            f32x4 x3 = *(const f32x4*)&XMT(d, 12);
            cl0 += x0 * wgv; cl1 += x1 * wgv; cl2 += x2 * wgv; cl3 += x3 * wgv;
            nz0 += x0 * wnv; nz1 += x1 * wnv; nz2 += x2 * wnv; nz3 += x3 * wnv;
        }
        *(f32x4*)&redc[sl][e][0]  = cl0; *(f32x4*)&redc[sl][e][4]  = cl1;
        *(f32x4*)&redc[sl][e][8]  = cl2; *(f32x4*)&redc[sl][e][12] = cl3;
        *(f32x4*)&redn[sl][e][0]  = nz0; *(f32x4*)&redn[sl][e][4]  = nz1;
        *(f32x4*)&redn[sl][e][8]  = nz2; *(f32x4*)&redn[sl][e][12] = nz3;
    }
    __syncthreads();

    // 3) finish logits per (b,e)
    for (int idx = t; idx < B_ * E_; idx += 192) {
        int bb = idx >> 4, e = idx & 15;
        float c2 = 0.f, n2 = 0.f;
        #pragma unroll
        for (int sl = 0; sl < 12; ++sl) { c2 += redc[sl][e][bb]; n2 += redn[sl][e][bb]; }
        float sp     = fmaxf(n2, 0.f) + log1pf(expf(-fabsf(n2)));  // softplus
        float stddev = sp + 0.01f;                                  // + NOISE_EPS
        float ny     = c2 + noise[bb * E_ + e] * stddev;
        s_clean[bb][e] = c2;
        s_std[bb][e]   = stddev;
        s_noisy[bb][e] = ny;
    }
    __syncthreads();

    // 4) rank / thresholds / softmax gates
    float sig = 1.f / (1.f + expf(-thr_ptr[0]));
    for (int idx = t; idx < B_ * E_; idx += 192) {
        int bb = idx >> 4, e = idx & 15;
        float ny = s_noisy[bb][e];
        int rank = 0;
        #pragma unroll
        for (int j = 0; j < E_; ++j) {
            float vj = s_noisy[bb][j];
            if (vj > ny || (vj == ny && j < e)) rank++;
        }
        if (rank == K_)     thrin_s[bb]  = ny;   // (K+1)-th largest
        if (rank == K_ - 1) throut_s[bb] = ny;   // K-th largest
        float mx = -1e30f;
        #pragma unroll
        for (int j = 0; j < E_; ++j) mx = fmaxf(mx, s_noisy[bb][j]);
        float den = 0.f;
        #pragma unroll
        for (int j = 0; j < E_; ++j) den += expf(s_noisy[bb][j] - mx);
        float gate = expf(ny - mx) / den;
        float sg   = fmaxf(gate - sig, 0.f);     // gates>0 so == sign*relu(|.|-sig)
        gsl[bb][e] = sg;
        gates_g[idx] = sg;
    }
    __syncthreads();

    // 5) cv^2 loss
    if (t < E_) {
        float imp = 0.f, ld = 0.f;
        #pragma unroll
        for (int bb = 0; bb < B_; ++bb) {
            imp += gsl[bb][t];
            float ti = thrin_s[bb], to = throut_s[bb];
            float c2 = s_clean[bb][t], sd = s_std[bb][t], nl = s_noisy[bb][t];
            float z  = (nl > ti) ? (c2 - ti) / sd : (c2 - to) / sd;
            ld += 0.5f * erfcf(-z * 0.70710678118654752f);   // Phi(z)
        }
        s_imp[t]  = imp;
        s_load[t] = ld;
    }
    __syncthreads();
    if (t == 0) {
        float m1 = 0.f, m2 = 0.f;
        #pragma unroll
        for (int j = 0; j < E_; ++j) { m1 += s_imp[j]; m2 += s_load[j]; }
        m1 /= E_; m2 /= E_;
        float v1 = 0.f, v2 = 0.f;
        #pragma unroll
        for (int j = 0; j < E_; ++j) {
            float a = s_imp[j]  - m1; v1 += a * a;
            float c = s_load[j] - m2; v2 += c * c;
        }
        v1 /= (E_ - 1); v2 /= (E_ - 1);                      // ddof=1
        loss_out[0] = (v1 / (m1 * m1 + 1e-10f) + v2 / (m2 * m2 + 1e-10f)) * 0.01f;
    }
    #undef XMT
}

// ---- KB: Wb mix (blocks 0..575) + expert bias (576..623) ------------------------------
__global__ void kB_mix(const float* __restrict__ gates, const float* __restrict__ weight,
                       const float* __restrict__ bias,
                       __hip_bfloat16* __restrict__ wb, float* __restrict__ ebias) {
    __shared__ float g[B_ * E_];
    int t = threadIdx.x;
    g[t] = gates[t];
    __syncthreads();

    if (blockIdx.x >= 576) {                 // bias-mix tail blocks
        int idx = (blockIdx.x - 576) * 256 + t;
        int b = idx / D_, o = idx % D_;
        float acc = 0.f;
        #pragma unroll
        for (int e = 0; e < E_; ++e) acc += g[b * E_ + e] * bias[e * D_ + o];
        ebias[idx] = acc;
        return;
    }

    size_t base = ((size_t)blockIdx.x * 256 + t) * 4;
    float4 acc[B_];
    #pragma unroll
    for (int b = 0; b < B_; ++b) acc[b] = make_float4(0.f, 0.f, 0.f, 0.f);

    #pragma unroll
    for (int e = 0; e < E_; ++e) {
        float4 w4 = *(const float4*)(weight + (size_t)e * D_ * D_ + base);
        #pragma unroll
        for (int b = 0; b < B_; ++b) {
            float ge = g[b * E_ + e];
            acc[b].x += ge * w4.x; acc[b].y += ge * w4.y;
            acc[b].z += ge * w4.z; acc[b].w += ge * w4.w;
        }
    }
    #pragma unroll
    for (int b = 0; b < B_; ++b) {
        __hip_bfloat16 h0 = __float2bfloat16(acc[b].x);
        __hip_bfloat16 h1 = __float2bfloat16(acc[b].y);
        __hip_bfloat16 h2 = __float2bfloat16(acc[b].z);
        __hip_bfloat16 h3 = __float2bfloat16(acc[b].w);
        ushort4 pk;
        pk.x = *(unsigned short*)&h0; pk.y = *(unsigned short*)&h1;
        pk.z = *(unsigned short*)&h2; pk.w = *(unsigned short*)&h3;
        *(ushort4*)((unsigned short*)wb + (size_t)b * D_ * D_ + base) = pk;
    }
}

// ---- KC: batched GEMM, 128x96 tile, 512 blocks (2/CU), XCD-local b, T2 swizzle --------
#define BM 128
#define BN 96
#define BK 64
#define NT (D_ / BK)   // 12 K-tiles

__global__ __launch_bounds__(256, 2) void kC_gemm(const __hip_bfloat16* __restrict__ xb,
                                                  const __hip_bfloat16* __restrict__ wbm,
                                                  const float* __restrict__ ebias,
                                                  float* __restrict__ y) {
    __shared__ __hip_bfloat16 As[2][BM][BK];   // 32 KB
    __shared__ __hip_bfloat16 Bs[2][BN][BK];   // 24 KB

    int t = threadIdx.x;
    int wgid  = blockIdx.x;        // 0..511
    int xcd   = wgid & 7;
    int local = wgid >> 3;         // 0..63
    int b  = (xcd << 1) | (local & 1);
    int r2 = local >> 1;           // 0..31
    int bm = r2 & 3;               // 0..3  (512/128)
    int bn = r2 >> 2;              // 0..7  (768/96)

    const __hip_bfloat16* xp = xb  + (size_t)b * S_ * D_ + (size_t)(bm * BM) * D_;
    const __hip_bfloat16* wp = wbm + (size_t)b * D_ * D_ + (size_t)(bn * BN) * D_;

    int wave = t >> 6, lane = t & 63;
    int wm = wave >> 1, wn = wave & 1;         // 2x2 waves, each 64x48 out
    int lrow = lane & 15;
    int lk   = (lane >> 4) << 3;               // 0,8,16,24
    int swz  = (lrow & 7) << 3;                // read-side XOR (elem units)

    int lr  = lane >> 3;                       // 0..7
    int lcs = (((lane & 7) ^ lr) << 3);        // pre-swizzled source col (rule #21)

    f32x4 zero4 = {0.f, 0.f, 0.f, 0.f};
    f32x4 acc[4][3];
    #pragma unroll
    for (int m = 0; m < 4; ++m)
        #pragma unroll
        for (int n = 0; n < 3; ++n) acc[m][n] = zero4;

    #define STAGE(buf, k0)                                                          \
        do {                                                                        \
            _Pragma("unroll")                                                       \
            for (int i = 0; i < 4; ++i) {                                           \
                int r = wave * 32 + i * 8;                                          \
                GLOAD16(xp + (size_t)(r + lr) * D_ + (k0) + lcs, &As[buf][r][0]);   \
            }                                                                       \
            _Pragma("unroll")                                                       \
            for (int i = 0; i < 3; ++i) {                                           \
                int r = wave * 24 + i * 8;                                          \
                GLOAD16(wp + (size_t)(r + lr) * D_ + (k0) + lcs, &Bs[buf][r][0]);   \
            }                                                                       \
        } while (0)

    #define COMPUTE(buf)                                                            \
        do {                                                                        \
            _Pragma("unroll")                                                       \
            for (int kk = 0; kk < BK; kk += 32) {                                   \
                short8 afr[4], bfr[3];                                              \
                _Pragma("unroll")                                                   \
                for (int m = 0; m < 4; ++m)                                         \
                    afr[m] = *(const short8*)(&As[buf][wm * 64 + m * 16 + lrow]     \
                                                 [(kk + lk) ^ swz]);                \
                _Pragma("unroll")                                                   \
                for (int n = 0; n < 3; ++n)                                         \
                    bfr[n] = *(const short8*)(&Bs[buf][wn * 48 + n * 16 + lrow]     \
                                                 [(kk + lk) ^ swz]);                \
                _Pragma("unroll")                                                   \
                for (int m = 0; m < 4; ++m)                                         \
                    _Pragma("unroll")                                               \
                    for (int n = 0; n < 3; ++n)                                     \
                        acc[m][n] = __builtin_amdgcn_mfma_f32_16x16x32_bf16(        \
                            afr[m], bfr[n], acc[m][n], 0, 0, 0);                    \
            }                                                                       \
        } while (0)

    STAGE(0, 0);
    __syncthreads();
    int cur = 0;
    for (int kt = 0; kt < NT - 1; ++kt) {
        STAGE(cur ^ 1, (kt + 1) * BK);
        COMPUTE(cur);
        __syncthreads();
        cur ^= 1;
    }
    COMPUTE(cur);

    float* yp = y + (size_t)b * S_ * D_ + (size_t)(bm * BM) * D_ + bn * BN;
    const float* ep = ebias + (size_t)b * D_ + bn * BN;
    int crow = (lane >> 4) * 4;
    int ccol = lane & 15;
    #pragma unroll
    for (int n = 0; n < 3; ++n) {
        float eb = ep[wn * 48 + n * 16 + ccol];
        #pragma unroll
        for (int m = 0; m < 4; ++m) {
            #pragma unroll
            for (int j = 0; j < 4; ++j) {
                __builtin_nontemporal_store(acc[m][n][j] + eb,
                    yp + (size_t)(wm * 64 + m * 16 + crow + j) * D_ + wn * 48 + n * 16 + ccol);
            }
        }
    }
    #undef STAGE
    #undef COMPUTE
}

// -------------------------------------------------------------------------------------
extern "C" void kernel_launch(void* const* d_in, const int* in_sizes, int n_in,
                              void* d_out, int out_size, void* d_ws, size_t ws_size,
                              hipStream_t stream) {
    const float* x       = (const float*)d_in[0];
    const float* noise   = (const float*)d_in[1];
    const float* w_gate  = (const float*)d_in[2];
    const float* w_noise = (const float*)d_in[3];
    const float* thr     = (const float*)d_in[4];
    const float* weight  = (const float*)d_in[5];
    const float* bias    = (const float*)d_in[6];
    float* out = (float*)d_out;   // y [B*S*D] then loss [1]

    char* ws = (char*)d_ws;
    float*          partial = (float*)(ws + 0);               // 16*B*D f32 = 786432 B
    float*          gates   = (float*)(ws + 786432);          // B*E f32
    float*          ebias   = (float*)(ws + 787456);          // B*D f32 = 49152 B
    __hip_bfloat16* xb      = (__hip_bfloat16*)(ws + 839808);     // B*S*D bf16
    __hip_bfloat16* wb      = (__hip_bfloat16*)(ws + 13422720);   // B*D*D bf16
    unsigned int*   cnt     = (unsigned int*)(ws + 32297088);     // election counter
                                                                  // (monotone; mod-256)

    kA_cvt_gate<<<dim3(B_, 16), 192, 0, stream>>>(x, noise, w_gate, w_noise, thr,
                                                  xb, partial, gates,
                                                  out + (size_t)B_ * S_ * D_, cnt);
    kB_mix<<<624, 256, 0, stream>>>(gates, weight, bias, wb, ebias);
    kC_gemm<<<512, 256, 0, stream>>>(xb, wb, ebias, out);
}

// Round 16
// 85.907 us; speedup vs baseline: 1.1609x; 1.1609x over previous
//
#include <hip/hip_runtime.h>
#include <hip/hip_bf16.h>

#define B_ 16
#define S_ 512
#define D_ 768
#define E_ 16
#define K_ 4

typedef __attribute__((ext_vector_type(8))) short short8;
typedef __attribute__((ext_vector_type(4))) float f32x4;

#define GLOAD16(gp, lp)                                             \
    __builtin_amdgcn_global_load_lds(                               \
        (const __attribute__((address_space(1))) void*)(gp),        \
        (__attribute__((address_space(3))) void*)(lp), 16, 0, 0)

// ---------------- K1: column means (16 s-chunks) + x -> bf16, vectorized ---------------
__global__ void k1_mean_cvt(const float* __restrict__ x, __hip_bfloat16* __restrict__ xb,
                            float* __restrict__ partial) {
    int t  = threadIdx.x;          // 0..191
    int b  = blockIdx.x;           // 0..15
    int sc = blockIdx.y;           // 0..15 (s chunk of 32)
    size_t rowbase = ((size_t)b * S_ + (size_t)sc * 32) * D_ + t * 4;

    float4 acc = make_float4(0.f, 0.f, 0.f, 0.f);
    #pragma unroll 8
    for (int s = 0; s < 32; ++s) {
        float4 v = *(const float4*)(x + rowbase + (size_t)s * D_);
        acc.x += v.x; acc.y += v.y; acc.z += v.z; acc.w += v.w;
        __hip_bfloat16 h0 = __float2bfloat16(v.x);
        __hip_bfloat16 h1 = __float2bfloat16(v.y);
        __hip_bfloat16 h2 = __float2bfloat16(v.z);
        __hip_bfloat16 h3 = __float2bfloat16(v.w);
        ushort4 pk;
        pk.x = *(unsigned short*)&h0; pk.y = *(unsigned short*)&h1;
        pk.z = *(unsigned short*)&h2; pk.w = *(unsigned short*)&h3;
        *(ushort4*)((unsigned short*)xb + rowbase + (size_t)s * D_) = pk;
    }
    *(float4*)(partial + ((size_t)sc * B_ + b) * D_ + t * 4) = acc;
}

// ---------------- K2a: per-batch gating (16 blocks, d-parallel dot products) -----------
__global__ void k2a_logits(const float* __restrict__ partial,
                           const float* __restrict__ noise,
                           const float* __restrict__ w_gate,
                           const float* __restrict__ w_noise,
                           const float* __restrict__ thr_ptr,
                           float* __restrict__ gates_out,
                           float* __restrict__ clean_out,
                           float* __restrict__ std_out,
                           float* __restrict__ noisy_out,
                           float* __restrict__ thrin_out,
                           float* __restrict__ throut_out) {
    __shared__ float xm[D_];
    __shared__ float red[2][16][17];
    __shared__ float s_noisy[E_];

    int b = blockIdx.x, t = threadIdx.x;

    for (int d = t; d < D_; d += 256) {
        float s = 0.f;
        #pragma unroll
        for (int c = 0; c < 16; ++c) s += partial[((size_t)c * B_ + b) * D_ + d];
        xm[d] = s * (1.0f / S_);
    }
    __syncthreads();

    int e = t & 15, sl = t >> 4;
    const float* wg = w_gate  + (size_t)sl * 48 * E_ + e;
    const float* wn = w_noise + (size_t)sl * 48 * E_ + e;
    float cl = 0.f, nz = 0.f;
    #pragma unroll
    for (int i = 0; i < 48; ++i) {
        float xv = xm[sl * 48 + i];
        cl += xv * wg[(size_t)i * E_];
        nz += xv * wn[(size_t)i * E_];
    }
    red[0][sl][e] = cl;
    red[1][sl][e] = nz;
    __syncthreads();

    if (t < E_) {
        float c2 = 0.f, n2 = 0.f;
        #pragma unroll
        for (int s2 = 0; s2 < 16; ++s2) { c2 += red[0][s2][t]; n2 += red[1][s2][t]; }
        float sp     = fmaxf(n2, 0.f) + log1pf(expf(-fabsf(n2)));
        float stddev = sp + 0.01f;
        float ny     = c2 + noise[b * E_ + t] * stddev;
        s_noisy[t] = ny;
        clean_out[b * E_ + t] = c2;
        std_out[b * E_ + t]   = stddev;
        noisy_out[b * E_ + t] = ny;
    }
    __syncthreads();

    if (t < E_) {
        float ny = s_noisy[t];
        int rank = 0;
        #pragma unroll
        for (int j = 0; j < E_; ++j) {
            float vj = s_noisy[j];
            if (vj > ny || (vj == ny && j < t)) rank++;
        }
        if (rank == K_)     thrin_out[b]  = ny;
        if (rank == K_ - 1) throut_out[b] = ny;

        float mx = -1e30f;
        #pragma unroll
        for (int j = 0; j < E_; ++j) mx = fmaxf(mx, s_noisy[j]);
        float den = 0.f;
        #pragma unroll
        for (int j = 0; j < E_; ++j) den += expf(s_noisy[j] - mx);
        float gate = expf(ny - mx) / den;
        float sig  = 1.f / (1.f + expf(-thr_ptr[0]));
        gates_out[b * E_ + t] = fmaxf(gate - sig, 0.f);
    }
}

// ------- K3: Wb mix (blocks 0..575, DIAGNOSTIC x2) + ebias (576..623) + loss (624) -----
__global__ void k3_wb(const float* __restrict__ gates, const float* __restrict__ weight,
                      const float* __restrict__ bias,
                      const float* __restrict__ clean,
                      const float* __restrict__ stdv,
                      const float* __restrict__ noisyv,
                      const float* __restrict__ thrin,
                      const float* __restrict__ throut,
                      __hip_bfloat16* __restrict__ wb, float* __restrict__ ebias,
                      float* __restrict__ loss_out) {
    __shared__ float g[B_ * E_];
    int t = threadIdx.x;
    g[t] = gates[t];
    __syncthreads();

    if (blockIdx.x == 624) {                 // loss block
        __shared__ float s_imp[E_], s_load[E_];
        if (t < E_) {
            float imp = 0.f, ld = 0.f;
            #pragma unroll
            for (int bb = 0; bb < B_; ++bb) {
                imp += g[bb * E_ + t];
                float ti = thrin[bb], to = throut[bb];
                float c2 = clean[bb * E_ + t], sd = stdv[bb * E_ + t], nl = noisyv[bb * E_ + t];
                float z  = (nl > ti) ? (c2 - ti) / sd : (c2 - to) / sd;
                ld += 0.5f * erfcf(-z * 0.70710678118654752f);   // Phi(z)
            }
            s_imp[t]  = imp;
            s_load[t] = ld;
        }
        __syncthreads();
        if (t == 0) {
            float m1 = 0.f, m2 = 0.f;
            #pragma unroll
            for (int j = 0; j < E_; ++j) { m1 += s_imp[j]; m2 += s_load[j]; }
            m1 /= E_; m2 /= E_;
            float v1 = 0.f, v2 = 0.f;
            #pragma unroll
            for (int j = 0; j < E_; ++j) {
                float a = s_imp[j]  - m1; v1 += a * a;
                float c = s_load[j] - m2; v2 += c * c;
            }
            v1 /= (E_ - 1); v2 /= (E_ - 1);
            loss_out[0] = (v1 / (m1 * m1 + 1e-10f) + v2 / (m2 * m2 + 1e-10f)) * 0.01f;
        }
        return;
    }

    if (blockIdx.x >= 576) {                 // bias-mix tail blocks
        int idx = (blockIdx.x - 576) * 256 + t;
        int b = idx / D_, o = idx % D_;
        float acc = 0.f;
        #pragma unroll
        for (int e = 0; e < E_; ++e) acc += g[b * E_ + e] * bias[e * D_ + o];
        ebias[idx] = acc;
        return;
    }

    size_t base = ((size_t)blockIdx.x * 256 + t) * 4;

    // DIAGNOSTIC double-run: rep 0 and rep 1 compute and store IDENTICAL bytes
    // (idempotent stores). The weight pointer is laundered through an opaque asm
    // barrier each rep so the compiler must re-issue loads and FMAs (no CSE/hoist).
    // dur delta vs the single-run R9 baseline == warm kB mix time.
    const float* wptr = weight;
    for (int rep = 0; rep < 2; ++rep) {
        unsigned long long wp64 = (unsigned long long)wptr;
        asm volatile("" : "+s"(wp64));
        const float* w = (const float*)wp64;

        float4 acc[B_];
        #pragma unroll
        for (int b = 0; b < B_; ++b) acc[b] = make_float4(0.f, 0.f, 0.f, 0.f);

        #pragma unroll
        for (int e = 0; e < E_; ++e) {
            float4 w4 = *(const float4*)(w + (size_t)e * D_ * D_ + base);
            #pragma unroll
            for (int b = 0; b < B_; ++b) {
                float ge = g[b * E_ + e];
                acc[b].x += ge * w4.x; acc[b].y += ge * w4.y;
                acc[b].z += ge * w4.z; acc[b].w += ge * w4.w;
            }
        }
        #pragma unroll
        for (int b = 0; b < B_; ++b) {
            __hip_bfloat16 h0 = __float2bfloat16(acc[b].x);
            __hip_bfloat16 h1 = __float2bfloat16(acc[b].y);
            __hip_bfloat16 h2 = __float2bfloat16(acc[b].z);
            __hip_bfloat16 h3 = __float2bfloat16(acc[b].w);
            ushort4 pk;
            pk.x = *(unsigned short*)&h0; pk.y = *(unsigned short*)&h1;
            pk.z = *(unsigned short*)&h2; pk.w = *(unsigned short*)&h3;
            *(ushort4*)((unsigned short*)wb + (size_t)b * D_ * D_ + base) = pk;
        }
    }
}

// -- K4: batched GEMM, 128x96 tile, 512 blocks (2/CU), XCD-local b, T2 swizzle ----------
#define BM 128
#define BN 96
#define BK 64
#define NT (D_ / BK)   // 12 K-tiles

__global__ __launch_bounds__(256, 2) void k4_gemm(const __hip_bfloat16* __restrict__ xb,
                                                  const __hip_bfloat16* __restrict__ wbm,
                                                  const float* __restrict__ ebias,
                                                  float* __restrict__ y) {
    __shared__ __hip_bfloat16 As[2][BM][BK];   // 32 KB
    __shared__ __hip_bfloat16 Bs[2][BN][BK];   // 24 KB

    int t = threadIdx.x;
    int wgid  = blockIdx.x;        // 0..511
    int xcd   = wgid & 7;
    int local = wgid >> 3;         // 0..63
    int b  = (xcd << 1) | (local & 1);
    int r2 = local >> 1;           // 0..31
    int bm = r2 & 3;               // 0..3  (512/128)
    int bn = r2 >> 2;              // 0..7  (768/96)

    const __hip_bfloat16* xp = xb  + (size_t)b * S_ * D_ + (size_t)(bm * BM) * D_;
    const __hip_bfloat16* wp = wbm + (size_t)b * D_ * D_ + (size_t)(bn * BN) * D_;

    int wave = t >> 6, lane = t & 63;
    int wm = wave >> 1, wn = wave & 1;         // 2x2 waves, each 64x48 out
    int lrow = lane & 15;
    int lk   = (lane >> 4) << 3;               // 0,8,16,24
    int swz  = (lrow & 7) << 3;                // read-side XOR (elem units)

    int lr  = lane >> 3;                       // 0..7
    int lcs = (((lane & 7) ^ lr) << 3);        // pre-swizzled source col (rule #21)

    f32x4 zero4 = {0.f, 0.f, 0.f, 0.f};
    f32x4 acc[4][3];
    #pragma unroll
    for (int m = 0; m < 4; ++m)
        #pragma unroll
        for (int n = 0; n < 3; ++n) acc[m][n] = zero4;

    #define STAGE(buf, k0)                                                          \
        do {                                                                        \
            _Pragma("unroll")                                                       \
            for (int i = 0; i < 4; ++i) {                                           \
                int r = wave * 32 + i * 8;                                          \
                GLOAD16(xp + (size_t)(r + lr) * D_ + (k0) + lcs, &As[buf][r][0]);   \
            }                                                                       \
            _Pragma("unroll")                                                       \
            for (int i = 0; i < 3; ++i) {                                           \
                int r = wave * 24 + i * 8;                                          \
                GLOAD16(wp + (size_t)(r + lr) * D_ + (k0) + lcs, &Bs[buf][r][0]);   \
            }                                                                       \
        } while (0)

    #define COMPUTE(buf)                                                            \
        do {                                                                        \
            _Pragma("unroll")                                                       \
            for (int kk = 0; kk < BK; kk += 32) {                                   \
                short8 afr[4], bfr[3];                                              \
                _Pragma("unroll")                                                   \
                for (int m = 0; m < 4; ++m)                                         \
                    afr[m] = *(const short8*)(&As[buf][wm * 64 + m * 16 + lrow]     \
                                                 [(kk + lk) ^ swz]);                \
                _Pragma("unroll")                                                   \
                for (int n = 0; n < 3; ++n)                                         \
                    bfr[n] = *(const short8*)(&Bs[buf][wn * 48 + n * 16 + lrow]     \
                                                 [(kk + lk) ^ swz]);                \
                _Pragma("unroll")                                                   \
                for (int m = 0; m < 4; ++m)                                         \
                    _Pragma("unroll")                                               \
                    for (int n = 0; n < 3; ++n)                                     \
                        acc[m][n] = __builtin_amdgcn_mfma_f32_16x16x32_bf16(        \
                            afr[m], bfr[n], acc[m][n], 0, 0, 0);                    \
            }                                                                       \
        } while (0)

    STAGE(0, 0);
    __syncthreads();
    int cur = 0;
    for (int kt = 0; kt < NT - 1; ++kt) {
        STAGE(cur ^ 1, (kt + 1) * BK);
        COMPUTE(cur);
        __syncthreads();
        cur ^= 1;
    }
    COMPUTE(cur);

    float* yp = y + (size_t)b * S_ * D_ + (size_t)(bm * BM) * D_ + bn * BN;
    const float* ep = ebias + (size_t)b * D_ + bn * BN;
    int crow = (lane >> 4) * 4;
    int ccol = lane & 15;
    #pragma unroll
    for (int n = 0; n < 3; ++n) {
        float eb = ep[wn * 48 + n * 16 + ccol];
        #pragma unroll
        for (int m = 0; m < 4; ++m) {
            #pragma unroll
            for (int j = 0; j < 4; ++j) {
                __builtin_nontemporal_store(acc[m][n][j] + eb,
                    yp + (size_t)(wm * 64 + m * 16 + crow + j) * D_ + wn * 48 + n * 16 + ccol);
            }
        }
    }
    #undef STAGE
    #undef COMPUTE
}

// -------------------------------------------------------------------------------------
extern "C" void kernel_launch(void* const* d_in, const int* in_sizes, int n_in,
                              void* d_out, int out_size, void* d_ws, size_t ws_size,
                              hipStream_t stream) {
    const float* x       = (const float*)d_in[0];
    const float* noise   = (const float*)d_in[1];
    const float* w_gate  = (const float*)d_in[2];
    const float* w_noise = (const float*)d_in[3];
    const float* thr     = (const float*)d_in[4];
    const float* weight  = (const float*)d_in[5];
    const float* bias    = (const float*)d_in[6];
    float* out = (float*)d_out;   // y [B*S*D] then loss [1]

    char* ws = (char*)d_ws;
    float*          partial = (float*)(ws + 0);               // 16*B*D f32 = 786432 B
    float*          gates   = (float*)(ws + 786432);
    float*          clean   = (float*)(ws + 787456);
    float*          stdv    = (float*)(ws + 788480);
    float*          noisyv  = (float*)(ws + 789504);
    float*          thrin   = (float*)(ws + 790528);
    float*          throut  = (float*)(ws + 790592);
    float*          ebias   = (float*)(ws + 790656);          // B*D f32
    __hip_bfloat16* xb      = (__hip_bfloat16*)(ws + 839808);     // B*S*D bf16
    __hip_bfloat16* wb      = (__hip_bfloat16*)(ws + 13422720);   // B*D*D bf16

    k1_mean_cvt<<<dim3(B_, 16), 192, 0, stream>>>(x, xb, partial);
    k2a_logits<<<16, 256, 0, stream>>>(partial, noise, w_gate, w_noise, thr, gates,
                                       clean, stdv, noisyv, thrin, throut);
    k3_wb<<<625, 256, 0, stream>>>(gates, weight, bias, clean, stdv, noisyv, thrin, throut,
                                   wb, ebias, out + (size_t)B_ * S_ * D_);
    k4_gemm<<<512, 256, 0, stream>>>(xb, wb, ebias, out);
}

// Round 17
// 50.961 us; speedup vs baseline: 1.9570x; 1.6857x over previous
//
#include <hip/hip_runtime.h>
#include <hip/hip_bf16.h>

#define B_ 16
#define S_ 512
#define D_ 768
#define E_ 16
#define K_ 4

typedef __attribute__((ext_vector_type(8))) short short8;
typedef __attribute__((ext_vector_type(4))) float f32x4;
typedef __attribute__((ext_vector_type(4))) unsigned short u16x4;

#define GLOAD16(gp, lp)                                             \
    __builtin_amdgcn_global_load_lds(                               \
        (const __attribute__((address_space(1))) void*)(gp),        \
        (__attribute__((address_space(3))) void*)(lp), 16, 0, 0)

__device__ __forceinline__ u16x4 pack_bf16x4(f32x4 v) {
    u16x4 pk;
    #pragma unroll
    for (int i = 0; i < 4; ++i) {
        __hip_bfloat16 h = __float2bfloat16(v[i]);
        pk[i] = *(unsigned short*)&h;
    }
    return pk;
}

// ---------------- K1: column means (16 s-chunks) + x -> bf16, vectorized ---------------
__global__ void k1_mean_cvt(const float* __restrict__ x, __hip_bfloat16* __restrict__ xb,
                            float* __restrict__ partial) {
    int t  = threadIdx.x;          // 0..191
    int b  = blockIdx.x;           // 0..15
    int sc = blockIdx.y;           // 0..15 (s chunk of 32)
    size_t rowbase = ((size_t)b * S_ + (size_t)sc * 32) * D_ + t * 4;

    float4 acc = make_float4(0.f, 0.f, 0.f, 0.f);
    #pragma unroll 8
    for (int s = 0; s < 32; ++s) {
        float4 v = *(const float4*)(x + rowbase + (size_t)s * D_);
        acc.x += v.x; acc.y += v.y; acc.z += v.z; acc.w += v.w;
        __hip_bfloat16 h0 = __float2bfloat16(v.x);
        __hip_bfloat16 h1 = __float2bfloat16(v.y);
        __hip_bfloat16 h2 = __float2bfloat16(v.z);
        __hip_bfloat16 h3 = __float2bfloat16(v.w);
        ushort4 pk;
        pk.x = *(unsigned short*)&h0; pk.y = *(unsigned short*)&h1;
        pk.z = *(unsigned short*)&h2; pk.w = *(unsigned short*)&h3;
        *(ushort4*)((unsigned short*)xb + rowbase + (size_t)s * D_) = pk;
    }
    *(float4*)(partial + ((size_t)sc * B_ + b) * D_ + t * 4) = acc;
}

// ---------------- K2a: per-batch gating (16 blocks, d-parallel dot products) -----------
__global__ void k2a_logits(const float* __restrict__ partial,
                           const float* __restrict__ noise,
                           const float* __restrict__ w_gate,
                           const float* __restrict__ w_noise,
                           const float* __restrict__ thr_ptr,
                           float* __restrict__ gates_out,
                           float* __restrict__ clean_out,
                           float* __restrict__ std_out,
                           float* __restrict__ noisy_out,
                           float* __restrict__ thrin_out,
                           float* __restrict__ throut_out) {
    __shared__ float xm[D_];
    __shared__ float red[2][16][17];
    __shared__ float s_noisy[E_];

    int b = blockIdx.x, t = threadIdx.x;

    for (int d = t; d < D_; d += 256) {
        float s = 0.f;
        #pragma unroll
        for (int c = 0; c < 16; ++c) s += partial[((size_t)c * B_ + b) * D_ + d];
        xm[d] = s * (1.0f / S_);
    }
    __syncthreads();

    int e = t & 15, sl = t >> 4;
    const float* wg = w_gate  + (size_t)sl * 48 * E_ + e;
    const float* wn = w_noise + (size_t)sl * 48 * E_ + e;
    float cl = 0.f, nz = 0.f;
    #pragma unroll
    for (int i = 0; i < 48; ++i) {
        float xv = xm[sl * 48 + i];
        cl += xv * wg[(size_t)i * E_];
        nz += xv * wn[(size_t)i * E_];
    }
    red[0][sl][e] = cl;
    red[1][sl][e] = nz;
    __syncthreads();

    if (t < E_) {
        float c2 = 0.f, n2 = 0.f;
        #pragma unroll
        for (int s2 = 0; s2 < 16; ++s2) { c2 += red[0][s2][t]; n2 += red[1][s2][t]; }
        float sp     = fmaxf(n2, 0.f) + log1pf(expf(-fabsf(n2)));
        float stddev = sp + 0.01f;
        float ny     = c2 + noise[b * E_ + t] * stddev;
        s_noisy[t] = ny;
        clean_out[b * E_ + t] = c2;
        std_out[b * E_ + t]   = stddev;
        noisy_out[b * E_ + t] = ny;
    }
    __syncthreads();

    if (t < E_) {
        float ny = s_noisy[t];
        int rank = 0;
        #pragma unroll
        for (int j = 0; j < E_; ++j) {
            float vj = s_noisy[j];
            if (vj > ny || (vj == ny && j < t)) rank++;
        }
        if (rank == K_)     thrin_out[b]  = ny;
        if (rank == K_ - 1) throut_out[b] = ny;

        float mx = -1e30f;
        #pragma unroll
        for (int j = 0; j < E_; ++j) mx = fmaxf(mx, s_noisy[j]);
        float den = 0.f;
        #pragma unroll
        for (int j = 0; j < E_; ++j) den += expf(s_noisy[j] - mx);
        float gate = expf(ny - mx) / den;
        float sig  = 1.f / (1.f + expf(-thr_ptr[0]));
        gates_out[b * E_ + t] = fmaxf(gate - sig, 0.f);
    }
}

// ------- K3: Wb mix, MLP-restructured (wave = b-quad; 16 loads in flight) --------------
// blocks 0..2303: mix (64 granules each; 4 waves share granule lines via L2)
// blocks 2304..2351: ebias; block 2352: cv^2 loss
__global__ __launch_bounds__(256) void k3_wb(
        const float* __restrict__ gates, const float* __restrict__ weight,
        const float* __restrict__ bias,
        const float* __restrict__ clean,
        const float* __restrict__ stdv,
        const float* __restrict__ noisyv,
        const float* __restrict__ thrin,
        const float* __restrict__ throut,
        __hip_bfloat16* __restrict__ wb, float* __restrict__ ebias,
        float* __restrict__ loss_out) {
    __shared__ float g[B_ * E_];
    int t = threadIdx.x;
    g[t] = gates[t];
    __syncthreads();

    int blk = blockIdx.x;

    if (blk == 2352) {                       // loss block
        __shared__ float s_imp[E_], s_load[E_];
        if (t < E_) {
            float imp = 0.f, ld = 0.f;
            #pragma unroll
            for (int bb = 0; bb < B_; ++bb) {
                imp += g[bb * E_ + t];
                float ti = thrin[bb], to = throut[bb];
                float c2 = clean[bb * E_ + t], sd = stdv[bb * E_ + t], nl = noisyv[bb * E_ + t];
                float z  = (nl > ti) ? (c2 - ti) / sd : (c2 - to) / sd;
                ld += 0.5f * erfcf(-z * 0.70710678118654752f);   // Phi(z)
            }
            s_imp[t]  = imp;
            s_load[t] = ld;
        }
        __syncthreads();
        if (t == 0) {
            float m1 = 0.f, m2 = 0.f;
            #pragma unroll
            for (int j = 0; j < E_; ++j) { m1 += s_imp[j]; m2 += s_load[j]; }
            m1 /= E_; m2 /= E_;
            float v1 = 0.f, v2 = 0.f;
            #pragma unroll
            for (int j = 0; j < E_; ++j) {
                float a = s_imp[j]  - m1; v1 += a * a;
                float c = s_load[j] - m2; v2 += c * c;
            }
            v1 /= (E_ - 1); v2 /= (E_ - 1);                      // ddof=1
            loss_out[0] = (v1 / (m1 * m1 + 1e-10f) + v2 / (m2 * m2 + 1e-10f)) * 0.01f;
        }
        return;
    }

    if (blk >= 2304) {                       // bias-mix tail blocks
        int idx = (blk - 2304) * 256 + t;    // 0..12287 = B_*D_
        int b = idx / D_, o = idx % D_;
        float acc = 0.f;
        #pragma unroll
        for (int e = 0; e < E_; ++e) acc += g[b * E_ + e] * bias[e * D_ + o];
        ebias[idx] = acc;
        return;
    }

    // mix: wave q handles b in [4q, 4q+4) over the block's 64 consecutive granules.
    // acc = 4 f32x4 = 16 VGPRs -> all 16 expert loads stay in flight (MLP fix);
    // waves 1..3 re-read wave 0's lines -> L2 hits, HBM traffic = weight once.
    int gran = blk * 64 + (t & 63);          // float4-granule of D*D
    int q    = t >> 6;                        // wave id = b-quad
    size_t base = (size_t)gran * 4;

    f32x4 acc0 = {0.f,0.f,0.f,0.f}, acc1 = {0.f,0.f,0.f,0.f};
    f32x4 acc2 = {0.f,0.f,0.f,0.f}, acc3 = {0.f,0.f,0.f,0.f};
    #pragma unroll
    for (int e = 0; e < E_; ++e) {
        f32x4 w4 = *(const f32x4*)(weight + (size_t)e * D_ * D_ + base);
        acc0 += g[(q * 4 + 0) * E_ + e] * w4;
        acc1 += g[(q * 4 + 1) * E_ + e] * w4;
        acc2 += g[(q * 4 + 2) * E_ + e] * w4;
        acc3 += g[(q * 4 + 3) * E_ + e] * w4;
    }
    unsigned short* wbp = (unsigned short*)wb;
    *(u16x4*)(wbp + (size_t)(q * 4 + 0) * D_ * D_ + base) = pack_bf16x4(acc0);
    *(u16x4*)(wbp + (size_t)(q * 4 + 1) * D_ * D_ + base) = pack_bf16x4(acc1);
    *(u16x4*)(wbp + (size_t)(q * 4 + 2) * D_ * D_ + base) = pack_bf16x4(acc2);
    *(u16x4*)(wbp + (size_t)(q * 4 + 3) * D_ * D_ + base) = pack_bf16x4(acc3);
}

// -- K4: batched GEMM, 128x96 tile, 512 blocks (2/CU), XCD-local b, T2 swizzle ----------
#define BM 128
#define BN 96
#define BK 64
#define NT (D_ / BK)   // 12 K-tiles

__global__ __launch_bounds__(256, 2) void k4_gemm(const __hip_bfloat16* __restrict__ xb,
                                                  const __hip_bfloat16* __restrict__ wbm,
                                                  const float* __restrict__ ebias,
                                                  float* __restrict__ y) {
    __shared__ __hip_bfloat16 As[2][BM][BK];   // 32 KB
    __shared__ __hip_bfloat16 Bs[2][BN][BK];   // 24 KB

    int t = threadIdx.x;
    int wgid  = blockIdx.x;        // 0..511
    int xcd   = wgid & 7;
    int local = wgid >> 3;         // 0..63
    int b  = (xcd << 1) | (local & 1);
    int r2 = local >> 1;           // 0..31
    int bm = r2 & 3;               // 0..3  (512/128)
    int bn = r2 >> 2;              // 0..7  (768/96)

    const __hip_bfloat16* xp = xb  + (size_t)b * S_ * D_ + (size_t)(bm * BM) * D_;
    const __hip_bfloat16* wp = wbm + (size_t)b * D_ * D_ + (size_t)(bn * BN) * D_;

    int wave = t >> 6, lane = t & 63;
    int wm = wave >> 1, wn = wave & 1;         // 2x2 waves, each 64x48 out
    int lrow = lane & 15;
    int lk   = (lane >> 4) << 3;               // 0,8,16,24
    int swz  = (lrow & 7) << 3;                // read-side XOR (elem units)

    int lr  = lane >> 3;                       // 0..7
    int lcs = (((lane & 7) ^ lr) << 3);        // pre-swizzled source col (rule #21)

    f32x4 zero4 = {0.f, 0.f, 0.f, 0.f};
    f32x4 acc[4][3];
    #pragma unroll
    for (int m = 0; m < 4; ++m)
        #pragma unroll
        for (int n = 0; n < 3; ++n) acc[m][n] = zero4;

    #define STAGE(buf, k0)                                                          \
        do {                                                                        \
            _Pragma("unroll")                                                       \
            for (int i = 0; i < 4; ++i) {                                           \
                int r = wave * 32 + i * 8;                                          \
                GLOAD16(xp + (size_t)(r + lr) * D_ + (k0) + lcs, &As[buf][r][0]);   \
            }                                                                       \
            _Pragma("unroll")                                                       \
            for (int i = 0; i < 3; ++i) {                                           \
                int r = wave * 24 + i * 8;                                          \
                GLOAD16(wp + (size_t)(r + lr) * D_ + (k0) + lcs, &Bs[buf][r][0]);   \
            }                                                                       \
        } while (0)

    #define COMPUTE(buf)                                                            \
        do {                                                                        \
            _Pragma("unroll")                                                       \
            for (int kk = 0; kk < BK; kk += 32) {                                   \
                short8 afr[4], bfr[3];                                              \
                _Pragma("unroll")                                                   \
                for (int m = 0; m < 4; ++m)                                         \
                    afr[m] = *(const short8*)(&As[buf][wm * 64 + m * 16 + lrow]     \
                                                 [(kk + lk) ^ swz]);                \
                _Pragma("unroll")                                                   \
                for (int n = 0; n < 3; ++n)                                         \
                    bfr[n] = *(const short8*)(&Bs[buf][wn * 48 + n * 16 + lrow]     \
                                                 [(kk + lk) ^ swz]);                \
                _Pragma("unroll")                                                   \
                for (int m = 0; m < 4; ++m)                                         \
                    _Pragma("unroll")                                               \
                    for (int n = 0; n < 3; ++n)                                     \
                        acc[m][n] = __builtin_amdgcn_mfma_f32_16x16x32_bf16(        \
                            afr[m], bfr[n], acc[m][n], 0, 0, 0);                    \
            }                                                                       \
        } while (0)

    STAGE(0, 0);
    __syncthreads();
    int cur = 0;
    for (int kt = 0; kt < NT - 1; ++kt) {
        STAGE(cur ^ 1, (kt + 1) * BK);
        COMPUTE(cur);
        __syncthreads();
        cur ^= 1;
    }
    COMPUTE(cur);

    float* yp = y + (size_t)b * S_ * D_ + (size_t)(bm * BM) * D_ + bn * BN;
    const float* ep = ebias + (size_t)b * D_ + bn * BN;
    int crow = (lane >> 4) * 4;
    int ccol = lane & 15;
    #pragma unroll
    for (int n = 0; n < 3; ++n) {
        float eb = ep[wn * 48 + n * 16 + ccol];
        #pragma unroll
        for (int m = 0; m < 4; ++m) {
            #pragma unroll
            for (int j = 0; j < 4; ++j) {
                __builtin_nontemporal_store(acc[m][n][j] + eb,
                    yp + (size_t)(wm * 64 + m * 16 + crow + j) * D_ + wn * 48 + n * 16 + ccol);
            }
        }
    }
    #undef STAGE
    #undef COMPUTE
}

// -------------------------------------------------------------------------------------
extern "C" void kernel_launch(void* const* d_in, const int* in_sizes, int n_in,
                              void* d_out, int out_size, void* d_ws, size_t ws_size,
                              hipStream_t stream) {
    const float* x       = (const float*)d_in[0];
    const float* noise   = (const float*)d_in[1];
    const float* w_gate  = (const float*)d_in[2];
    const float* w_noise = (const float*)d_in[3];
    const float* thr     = (const float*)d_in[4];
    const float* weight  = (const float*)d_in[5];
    const float* bias    = (const float*)d_in[6];
    float* out = (float*)d_out;   // y [B*S*D] then loss [1]

    char* ws = (char*)d_ws;
    float*          partial = (float*)(ws + 0);               // 16*B*D f32 = 786432 B
    float*          gates   = (float*)(ws + 786432);
    float*          clean   = (float*)(ws + 787456);
    float*          stdv    = (float*)(ws + 788480);
    float*          noisyv  = (float*)(ws + 789504);
    float*          thrin   = (float*)(ws + 790528);
    float*          throut  = (float*)(ws + 790592);
    float*          ebias   = (float*)(ws + 790656);          // B*D f32
    __hip_bfloat16* xb      = (__hip_bfloat16*)(ws + 839808);     // B*S*D bf16
    __hip_bfloat16* wb      = (__hip_bfloat16*)(ws + 13422720);   // B*D*D bf16

    k1_mean_cvt<<<dim3(B_, 16), 192, 0, stream>>>(x, xb, partial);
    k2a_logits<<<16, 256, 0, stream>>>(partial, noise, w_gate, w_noise, thr, gates,
                                       clean, stdv, noisyv, thrin, throut);
    k3_wb<<<2353, 256, 0, stream>>>(gates, weight, bias, clean, stdv, noisyv, thrin, throut,
                                    wb, ebias, out + (size_t)B_ * S_ * D_);
    k4_gemm<<<512, 256, 0, stream>>>(xb, wb, ebias, out);
}